// Round 9
// baseline (454.304 us; speedup 1.0000x reference)
//
#include <hip/hip_runtime.h>
#include <hip/hip_bf16.h>
#include <math.h>

#define N_USERS 100000
#define N_ITEMS 50000
#define N_NODES 150000
#define N_EDGES 1000000
#define N_KEYS  (2 * N_NODES)      // row keys [0,N), col keys [N,2N)
#define N_GU_FLAT (N_USERS * 64)   // 6,400,000
#define N_ALL_FLAT (N_NODES * 64)  // 9,600,000
#define SCAN_BLK 512
#define N_SCAN_BLOCKS ((N_KEYS + SCAN_BLK - 1) / SCAN_BLK)

typedef __hip_bfloat16 bf16;
typedef unsigned short ushort_t;
typedef unsigned int uint_t;

__device__ __forceinline__ ushort_t f2bs(float f) {
    bf16 h = __float2bfloat16(f);
    return *reinterpret_cast<ushort_t*>(&h);
}
__device__ __forceinline__ float lo2f(uint_t u) {  // low bf16 of a packed pair
    float f; *reinterpret_cast<uint_t*>(&f) = u << 16; return f;
}
__device__ __forceinline__ float hi2f(uint_t u) {  // high bf16 of a packed pair
    float f; *reinterpret_cast<uint_t*>(&f) = u & 0xFFFF0000u; return f;
}
__device__ __forceinline__ uint_t pack2(float a, float b) {
    return (uint_t)f2bs(a) | ((uint_t)f2bs(b) << 16);
}

// ---------- Phase 1 (fused): rank atomics  ||  Gu/Gi -> bf16 xG ----------
__global__ __launch_bounds__(256) void dg_hist_cast(
        const int* __restrict__ ei,
        const float* __restrict__ Gu, const float* __restrict__ Gi, ushort_t* __restrict__ xG,
        ushort_t* __restrict__ rank_r, ushort_t* __restrict__ rank_c,
        int* __restrict__ cnt2, int gE) {
    int b = blockIdx.x;
    if (b >= gE) {
        long base = ((long)(b - gE) * 256 + threadIdx.x) * 4;
        if (base >= N_ALL_FLAT) return;
        float4 v = (base < N_GU_FLAT) ? *(const float4*)(Gu + base)
                                      : *(const float4*)(Gi + (base - N_GU_FLAT));
        uint2 o;
        o.x = pack2(v.x, v.y);
        o.y = pack2(v.z, v.w);
        *(uint2*)(xG + base) = o;
        return;
    }
    int e = b * 256 + threadIdx.x;
    if (e >= N_EDGES) return;
    int r = ei[e];
    int c = ei[N_EDGES + e];
    rank_r[e] = (ushort_t)atomicAdd(&cnt2[r], 1);
    rank_c[e] = (ushort_t)atomicAdd(&cnt2[N_NODES + c], 1);
}

// ---------- Phase 2: exclusive scan of cnt2 -> offs ----------
__global__ void dg_scan1(const int* __restrict__ cnt2, int* __restrict__ offs,
                         int* __restrict__ partials) {
    __shared__ int s[SCAN_BLK];
    int t = threadIdx.x;
    int i = blockIdx.x * SCAN_BLK + t;
    int v = (i < N_KEYS) ? cnt2[i] : 0;
    s[t] = v;
    __syncthreads();
    for (int off = 1; off < SCAN_BLK; off <<= 1) {
        int a = (t >= off) ? s[t - off] : 0;
        __syncthreads();
        s[t] += a;
        __syncthreads();
    }
    int incl = s[t];
    if (i < N_KEYS) offs[i] = incl - v;
    if (t == SCAN_BLK - 1) partials[blockIdx.x] = incl;
}

__global__ void dg_scan2(int* __restrict__ partials) {
    __shared__ int s[1024];
    int t = threadIdx.x;
    int v = (t < N_SCAN_BLOCKS) ? partials[t] : 0;
    s[t] = v;
    __syncthreads();
    for (int off = 1; off < 1024; off <<= 1) {
        int a = (t >= off) ? s[t - off] : 0;
        __syncthreads();
        s[t] += a;
        __syncthreads();
    }
    if (t < N_SCAN_BLOCKS) partials[t] = (t > 0) ? s[t - 1] : 0;
}

__global__ void dg_scan3(int* __restrict__ offs, const int* __restrict__ partials) {
    int i = blockIdx.x * SCAN_BLK + threadIdx.x;
    if (i >= N_KEYS) return;
    offs[i] += partials[blockIdx.x];
}

// ---------- Phase 3: deterministic scatter; softmax recomputed here (no atomics) ----------
__global__ __launch_bounds__(256) void dg_scatter(
        const int* __restrict__ ei, const float* __restrict__ intents,
        const ushort_t* __restrict__ rank_r, const ushort_t* __restrict__ rank_c,
        const int* __restrict__ offs, uint2* __restrict__ row_w8,
        int* __restrict__ col_src, uint2* __restrict__ col_nw8) {
    int e = blockIdx.x * blockDim.x + threadIdx.x;
    if (e >= N_EDGES) return;
    float v0 = intents[e];
    float v1 = intents[N_EDGES + e];
    float v2 = intents[2 * N_EDGES + e];
    float v3 = intents[3 * N_EDGES + e];
    float m  = fmaxf(fmaxf(v0, v1), fmaxf(v2, v3));
    float e0 = __expf(v0 - m), e1 = __expf(v1 - m), e2 = __expf(v2 - m), e3 = __expf(v3 - m);
    float inv = 1.0f / (e0 + e1 + e2 + e3);
    uint2 wp;
    wp.x = pack2(e0 * inv, e1 * inv);
    wp.y = pack2(e2 * inv, e3 * inv);
    int r = ei[e];
    int c = ei[N_EDGES + e];
    row_w8[offs[r] + rank_r[e]] = wp;
    int pc = offs[N_NODES + c] - N_EDGES + rank_c[e];  // col entries indexed [0,E)
    col_src[pc] = r;
    col_nw8[pc] = wp;   // w for degdis; overwritten with norm by dg_norm
}

// ---------- Phase 4: deg = streaming bf16 sums over both CSR segments -> dis ----------
__global__ void dg_degdis(const int* __restrict__ cnt2, const int* __restrict__ offs,
                          const uint_t* __restrict__ row_w8, const uint_t* __restrict__ col_w8,
                          float* __restrict__ dis) {
    int t = blockIdx.x * blockDim.x + threadIdx.x;  // (node, k)
    if (t >= N_NODES * 4) return;
    int n = t >> 2, k = t & 3;
    int hw = k >> 1, odd = k & 1;
    float d = 0.f;
    int o = offs[n], c = cnt2[n];
    for (int i = 0; i < c; ++i) {
        uint_t u = row_w8[(long)(o + i) * 2 + hw];
        d += odd ? hi2f(u) : lo2f(u);
    }
    o = offs[N_NODES + n] - N_EDGES; c = cnt2[N_NODES + n];
    for (int i = 0; i < c; ++i) {
        uint_t u = col_w8[(long)(o + i) * 2 + hw];
        d += odd ? hi2f(u) : lo2f(u);
    }
    dis[t] = (d > 0.f) ? rsqrtf(fmaxf(d, 1e-12f)) : 0.f;
}

// ---------- Phase 5: norm = dis[src]*dis[dst] -> bf16x4, one lane per edge ----------
__global__ __launch_bounds__(256) void dg_norm(const int* __restrict__ cnt2,
                                               const int* __restrict__ offs,
                                               const int* __restrict__ col_src,
                                               uint2* __restrict__ col_nw8,
                                               const float* __restrict__ dis) {
    int wid  = (blockIdx.x * blockDim.x + threadIdx.x) >> 6;  // node
    int lane = threadIdx.x & 63;
    if (wid >= N_NODES) return;
    int base = offs[N_NODES + wid] - N_EDGES;
    int cnt  = cnt2[N_NODES + wid];
    float4 dn = *(const float4*)(dis + wid * 4);  // wave-uniform
    for (int i = lane; i < cnt; i += 64) {
        long idx = base + i;
        int src  = col_src[idx];                          // coalesced 4B
        float4 ds = *(const float4*)(dis + (long)src * 4); // 16B gather (L2-resident)
        uint2 nv;
        nv.x = pack2(ds.x * dn.x, ds.y * dn.y);
        nv.y = pack2(ds.z * dn.z, ds.w * dn.w);
        col_nw8[idx] = nv;                                 // coalesced 8B
    }
}

// ---------- Phase 6: aggregation — 8 edges/wave-iter, tail subgroups masked ----------
// lanes: g = lane>>3 (edge subgroup), j = lane&7 (comps 8j..8j+7, intent k = j>>1)
template <int LAST>
__global__ __launch_bounds__(256) void dg_agg(const ushort_t* __restrict__ xin,
                                              ushort_t* __restrict__ xout_b,
                                              float* __restrict__ xout_f,
                                              const int* __restrict__ col_src,
                                              const uint2* __restrict__ col_nw8,
                                              const int* __restrict__ cnt2,
                                              const int* __restrict__ offs) {
    int wid  = (blockIdx.x * blockDim.x + threadIdx.x) >> 6;
    int lane = threadIdx.x & 63;
    if (wid >= N_NODES) return;
    int base = offs[N_NODES + wid] - N_EDGES;
    int cnt  = cnt2[N_NODES + wid];
    int g = lane >> 3, j = lane & 7, k = j >> 1;
    float a0 = 0.f, a1 = 0.f, a2 = 0.f, a3 = 0.f;
    float a4 = 0.f, a5 = 0.f, a6 = 0.f, a7 = 0.f;
    for (int i = 0; i < cnt; i += 8) {
        int ii = i + g;
        if (ii < cnt) {                                // subgroup-uniform mask:
            long idx = base + ii;                      // idle subgroups issue NO loads
            int src  = col_src[idx];                   // 4B broadcast per subgroup
            uint2 nw = col_nw8[idx];                   // 8B broadcast per subgroup
            uint_t pair = (k < 2) ? nw.x : nw.y;
            float nk = (k & 1) ? hi2f(pair) : lo2f(pair);
            uint4 xu = *(const uint4*)(xin + (long)src * 64 + j * 8);  // 16B/lane
            a0 = fmaf(nk, lo2f(xu.x), a0);
            a1 = fmaf(nk, hi2f(xu.x), a1);
            a2 = fmaf(nk, lo2f(xu.y), a2);
            a3 = fmaf(nk, hi2f(xu.y), a3);
            a4 = fmaf(nk, lo2f(xu.z), a4);
            a5 = fmaf(nk, hi2f(xu.z), a5);
            a6 = fmaf(nk, lo2f(xu.w), a6);
            a7 = fmaf(nk, hi2f(xu.w), a7);
        }
    }
    // reduce the 8 edge subgroups (xor 8,16,32 over lanes)
    a0 += __shfl_xor(a0, 8); a0 += __shfl_xor(a0, 16); a0 += __shfl_xor(a0, 32);
    a1 += __shfl_xor(a1, 8); a1 += __shfl_xor(a1, 16); a1 += __shfl_xor(a1, 32);
    a2 += __shfl_xor(a2, 8); a2 += __shfl_xor(a2, 16); a2 += __shfl_xor(a2, 32);
    a3 += __shfl_xor(a3, 8); a3 += __shfl_xor(a3, 16); a3 += __shfl_xor(a3, 32);
    a4 += __shfl_xor(a4, 8); a4 += __shfl_xor(a4, 16); a4 += __shfl_xor(a4, 32);
    a5 += __shfl_xor(a5, 8); a5 += __shfl_xor(a5, 16); a5 += __shfl_xor(a5, 32);
    a6 += __shfl_xor(a6, 8); a6 += __shfl_xor(a6, 16); a6 += __shfl_xor(a6, 32);
    a7 += __shfl_xor(a7, 8); a7 += __shfl_xor(a7, 16); a7 += __shfl_xor(a7, 32);
    if (g == 0) {
        long o = (long)wid * 64 + j * 8;
        if (LAST) {
            *(float4*)(xout_f + o)     = make_float4(a0, a1, a2, a3);
            *(float4*)(xout_f + o + 4) = make_float4(a4, a5, a6, a7);
        } else {
            uint4 ob;
            ob.x = pack2(a0, a1); ob.y = pack2(a2, a3);
            ob.z = pack2(a4, a5); ob.w = pack2(a6, a7);
            *(uint4*)(xout_b + o) = ob;                // 16B/lane, 128B/node
        }
    }
}

extern "C" void kernel_launch(void* const* d_in, const int* in_sizes, int n_in,
                              void* d_out, int out_size, void* d_ws, size_t ws_size,
                              hipStream_t stream) {
    const float* Gu      = (const float*)d_in[0];   // [100000, 64] f32
    const float* Gi      = (const float*)d_in[1];   // [50000, 64]  f32
    const int*   ei      = (const int*)d_in[2];     // [2, 1000000] int32
    const float* intents = (const float*)d_in[3];   // [4, 1000000] f32
    float* out = (float*)d_out;                      // [150000, 4, 16] f32

    // ---- workspace layout (~87 MB) ----
    char* ws = (char*)d_ws;
    size_t off = 0;
    uint2* row_w8 = (uint2*)(ws + off);  off += (size_t)N_EDGES * 8;    // 8 MB
    ushort_t* rank_r = (ushort_t*)(ws + off); off += (size_t)N_EDGES * 2;
    ushort_t* rank_c = (ushort_t*)(ws + off); off += (size_t)N_EDGES * 2;
    int* col_src = (int*)(ws + off);     off += (size_t)N_EDGES * 4;    // 4 MB
    uint2* col_nw8 = (uint2*)(ws + off); off += (size_t)N_EDGES * 8;    // 8 MB (w, then norm)
    int* cnt2 = (int*)(ws + off);        off += (size_t)N_KEYS * 4;
    int* offs = (int*)(ws + off);        off += (size_t)N_KEYS * 4;
    int* partials = (int*)(ws + off);    off += 4096;
    float* dis = (float*)(ws + off);     off += (size_t)N_NODES * 4 * 4;
    ushort_t* xG = (ushort_t*)(ws + off); off += (size_t)N_ALL_FLAT * 2;  // 19.2 MB
    ushort_t* xA = (ushort_t*)(ws + off); off += (size_t)N_ALL_FLAT * 2;  // 19.2 MB
    ushort_t* xB = (ushort_t*)(ws + off); off += (size_t)N_ALL_FLAT * 2;  // 19.2 MB
    (void)ws_size; (void)in_sizes; (void)n_in; (void)out_size;

    hipMemsetAsync(cnt2, 0, (size_t)N_KEYS * sizeof(int), stream);

    const int BLK = 256;
    int gE = (N_EDGES + BLK - 1) / BLK;                 // 3907 edge blocks
    int gC = (N_ALL_FLAT / 4 + BLK - 1) / BLK;          // 9375 cast blocks

    dg_hist_cast<<<gE + gC, BLK, 0, stream>>>(ei, Gu, Gi, xG, rank_r, rank_c, cnt2, gE);
    dg_scan1<<<N_SCAN_BLOCKS, SCAN_BLK, 0, stream>>>(cnt2, offs, partials);
    dg_scan2<<<1, 1024, 0, stream>>>(partials);
    dg_scan3<<<N_SCAN_BLOCKS, SCAN_BLK, 0, stream>>>(offs, partials);
    dg_scatter<<<gE, BLK, 0, stream>>>(ei, intents, rank_r, rank_c, offs, row_w8, col_src, col_nw8);
    dg_degdis<<<(N_NODES * 4 + BLK - 1) / BLK, BLK, 0, stream>>>(
        cnt2, offs, (const uint_t*)row_w8, (const uint_t*)col_nw8, dis);
    dg_norm<<<(N_NODES * 64 + BLK - 1) / BLK, BLK, 0, stream>>>(cnt2, offs, col_src, col_nw8, dis);

    int gN = (N_NODES * 64 + BLK - 1) / BLK;  // one 64-lane wave per node
    dg_agg<0><<<gN, BLK, 0, stream>>>(xG, xA, nullptr, col_src, col_nw8, cnt2, offs);
    dg_agg<0><<<gN, BLK, 0, stream>>>(xA, xB, nullptr, col_src, col_nw8, cnt2, offs);
    dg_agg<1><<<gN, BLK, 0, stream>>>(xB, nullptr, out, col_src, col_nw8, cnt2, offs);
}